// Round 1
// baseline (1029.703 us; speedup 1.0000x reference)
//
#include <hip/hip_runtime.h>
#include <hip/hip_fp16.h>

// MoE top-2 SwiGLU, MI355X. Sparse (top-2) grouped-GEMM formulation:
//   router -> per-expert BM-aligned slot segments -> GEMM1 (x@w1^T, x@w3^T fused,
//   silu*mul -> h fp16) -> GEMM2 (h@w2^T -> y fp32 per slot) -> combine.
// fp16 MFMA (16x16x32, fp32 accum). Workspace need ~433 MB.

#define NTOK 8192
#define D_ 1024
#define F_ 4096
#define E_ 8
#define BM 128
#define BN 128
#define BK 32
#define SLOT_CAP (NTOK * 2 + E_ * BM) // 17408
#define NRB (SLOT_CAP / BM)           // 136 row-blocks (fixed grid)

using half8 = __attribute__((ext_vector_type(8))) _Float16;
using half4 = __attribute__((ext_vector_type(4))) _Float16;
using f32x4 = __attribute__((ext_vector_type(4))) float;

__device__ __forceinline__ void gload16(const void* g, void* l) {
  __builtin_amdgcn_global_load_lds((const __attribute__((address_space(1))) void*)g,
                                   (__attribute__((address_space(3))) void*)l, 16, 0, 0);
}

// ---------------- fp32 -> fp16 convert (vectorized) ----------------
__global__ __launch_bounds__(256) void cvt_kernel(const float* __restrict__ src,
                                                  _Float16* __restrict__ dst, int n4) {
  int i = blockIdx.x * 256 + threadIdx.x;
  int stride = gridDim.x * 256;
  for (; i < n4; i += stride) {
    float4 v = ((const float4*)src)[i];
    half4 h;
    h.x = (_Float16)v.x; h.y = (_Float16)v.y; h.z = (_Float16)v.z; h.w = (_Float16)v.w;
    ((half4*)dst)[i] = h;
  }
}

// ---------------- router: logits -> softmax -> top2 -> renorm gates ----------------
__global__ __launch_bounds__(256) void router_kernel(
    const float* __restrict__ x, const float* __restrict__ rw, const float* __restrict__ rbias,
    int* __restrict__ tok_e, float* __restrict__ tok_g, int* __restrict__ counts) {
  int wv = threadIdx.x >> 6, lane = threadIdx.x & 63;
  int t = blockIdx.x * 4 + wv; // one wave per token
  const float4* xr = (const float4*)(x + (size_t)t * D_);
  float acc[E_];
#pragma unroll
  for (int e = 0; e < E_; ++e) acc[e] = 0.f;
  for (int i = lane; i < D_ / 4; i += 64) {
    float4 xv = xr[i];
#pragma unroll
    for (int e = 0; e < E_; ++e) {
      float4 wv4 = ((const float4*)(rw + (size_t)e * D_))[i];
      acc[e] += xv.x * wv4.x + xv.y * wv4.y + xv.z * wv4.z + xv.w * wv4.w;
    }
  }
#pragma unroll
  for (int e = 0; e < E_; ++e) {
#pragma unroll
    for (int off = 32; off > 0; off >>= 1) acc[e] += __shfl_down(acc[e], off);
  }
  if (lane == 0) {
    float p[E_], mx = -1e30f;
#pragma unroll
    for (int e = 0; e < E_; ++e) { p[e] = acc[e] + rbias[e]; mx = fmaxf(mx, p[e]); }
#pragma unroll
    for (int e = 0; e < E_; ++e) p[e] = expf(p[e] - mx);
    int i0 = 0;
#pragma unroll
    for (int e = 1; e < E_; ++e) if (p[e] > p[i0]) i0 = e;
    int i1 = (i0 == 0) ? 1 : 0;
#pragma unroll
    for (int e = 0; e < E_; ++e) if (e != i0 && p[e] > p[i1]) i1 = e;
    float s = p[i0] + p[i1];
    tok_e[t * 2] = i0; tok_e[t * 2 + 1] = i1;
    tok_g[t * 2] = p[i0] / s; tok_g[t * 2 + 1] = p[i1] / s;
    atomicAdd(&counts[i0], 1); atomicAdd(&counts[i1], 1);
  }
}

__global__ void init_kernel(int* slot_token, int* counts, int* cursor) {
  int i = blockIdx.x * 256 + threadIdx.x;
  if (blockIdx.x == 0 && threadIdx.x < E_) { counts[threadIdx.x] = 0; cursor[threadIdx.x] = 0; }
  if (i < SLOT_CAP) slot_token[i] = 0; // padding slots -> token 0 (finite garbage, never combined)
}

__global__ void scan_kernel(const int* __restrict__ counts, int* __restrict__ offs) {
  if (threadIdx.x == 0) {
    int o = 0;
    for (int e = 0; e < E_; ++e) { offs[e] = o; o += ((counts[e] + BM - 1) / BM) * BM; }
    offs[E_] = o;
  }
}

__global__ void scatter_kernel(const int* __restrict__ tok_e, const int* __restrict__ offs,
                               int* __restrict__ cursor, int* __restrict__ slot_token,
                               int* __restrict__ slot_of) {
  int i = blockIdx.x * 256 + threadIdx.x; // i = token*2 + k
  if (i >= NTOK * 2) return;
  int e = tok_e[i];
  int pos = offs[e] + atomicAdd(&cursor[e], 1);
  slot_token[pos] = i >> 1;
  slot_of[i] = pos;
}

// ---------------- GEMM1: h[slot,F] = silu(x@w1[e]^T) * (x@w3[e]^T) ----------------
__global__ __launch_bounds__(256, 2) void gemm1_kernel(
    const _Float16* __restrict__ x16, const _Float16* __restrict__ w1h,
    const _Float16* __restrict__ w3h, const int* __restrict__ slot_token,
    const int* __restrict__ offs, _Float16* __restrict__ hbuf) {
  __shared__ _Float16 lA[BM * BK], lB1[BN * BK], lB3[BN * BK];
  int rb = blockIdx.x, nb = blockIdx.y;
  int row0 = rb * BM;
  if (row0 >= offs[E_]) return;
  int e = 0;
#pragma unroll
  for (int i = 1; i < E_; ++i) if (row0 >= offs[i]) e = i;

  int tid = threadIdx.x, lane = tid & 63, wv = tid >> 6;
  int srow = tid >> 2;       // 0..63: staging row within 64-row half-tile
  int scol = (tid & 3) * 8;  // 8 halves = 16B per lane
  int tokA0 = slot_token[row0 + srow];
  int tokA1 = slot_token[row0 + srow + 64];
  const _Float16* gA0 = x16 + (size_t)tokA0 * D_ + scol;
  const _Float16* gA1 = x16 + (size_t)tokA1 * D_ + scol;
  size_t woff = (size_t)e * F_ * D_ + (size_t)(nb * BN + srow) * D_ + scol;
  const _Float16* gB1 = w1h + woff;
  const _Float16* gB3 = w3h + woff;
  const size_t DSTEP = (size_t)64 * D_;

  _Float16* dA0 = lA + (wv * 16) * BK;
  _Float16* dA1 = lA + (64 + wv * 16) * BK;
  _Float16* dB1a = lB1 + (wv * 16) * BK;
  _Float16* dB1b = lB1 + (64 + wv * 16) * BK;
  _Float16* dB3a = lB3 + (wv * 16) * BK;
  _Float16* dB3b = lB3 + (64 + wv * 16) * BK;

  int wr = wv >> 1, wc = wv & 1;
  int fr = lane & 15, kq = (lane >> 4) * 8;
  const _Float16* pA = lA + (wr * 64 + fr) * BK + kq;
  const _Float16* pB1 = lB1 + (wc * 64 + fr) * BK + kq;
  const _Float16* pB3 = lB3 + (wc * 64 + fr) * BK + kq;

  f32x4 acc1[4][4], acc3[4][4];
  f32x4 z = {0.f, 0.f, 0.f, 0.f};
#pragma unroll
  for (int m = 0; m < 4; ++m)
#pragma unroll
    for (int n = 0; n < 4; ++n) { acc1[m][n] = z; acc3[m][n] = z; }

  for (int ks = 0; ks < D_ / BK; ++ks) {
    int k0 = ks * BK;
    gload16(gA0 + k0, dA0);
    gload16(gA1 + k0, dA1);
    gload16(gB1 + k0, dB1a);
    gload16(gB1 + DSTEP + k0, dB1b);
    gload16(gB3 + k0, dB3a);
    gload16(gB3 + DSTEP + k0, dB3b);
    __syncthreads();
    half8 a[4], b1[4], b3[4];
#pragma unroll
    for (int m = 0; m < 4; ++m) a[m] = *(const half8*)(pA + m * 16 * BK);
#pragma unroll
    for (int n = 0; n < 4; ++n) {
      b1[n] = *(const half8*)(pB1 + n * 16 * BK);
      b3[n] = *(const half8*)(pB3 + n * 16 * BK);
    }
#pragma unroll
    for (int m = 0; m < 4; ++m)
#pragma unroll
      for (int n = 0; n < 4; ++n) {
        acc1[m][n] = __builtin_amdgcn_mfma_f32_16x16x32_f16(a[m], b1[n], acc1[m][n], 0, 0, 0);
        acc3[m][n] = __builtin_amdgcn_mfma_f32_16x16x32_f16(a[m], b3[n], acc3[m][n], 0, 0, 0);
      }
    __syncthreads();
  }

  int r0 = row0 + wr * 64 + (lane >> 4) * 4;
  int c0 = nb * BN + wc * 64 + (lane & 15);
#pragma unroll
  for (int m = 0; m < 4; ++m)
#pragma unroll
    for (int n = 0; n < 4; ++n)
#pragma unroll
      for (int i = 0; i < 4; ++i) {
        float g = acc1[m][n][i], u = acc3[m][n][i];
        float hv = g / (1.f + __expf(-g)) * u; // silu(g)*u
        hbuf[(size_t)(r0 + m * 16 + i) * F_ + (c0 + n * 16)] = (_Float16)hv;
      }
}

// ---------------- GEMM2: y[slot,D] = h[slot,:] @ w2[e]^T ----------------
__global__ __launch_bounds__(256, 2) void gemm2_kernel(
    const _Float16* __restrict__ hbuf, const _Float16* __restrict__ w2h,
    const int* __restrict__ offs, float* __restrict__ ybuf) {
  __shared__ _Float16 lA[BM * BK], lB[BN * BK];
  int rb = blockIdx.x, nb = blockIdx.y;
  int row0 = rb * BM;
  if (row0 >= offs[E_]) return;
  int e = 0;
#pragma unroll
  for (int i = 1; i < E_; ++i) if (row0 >= offs[i]) e = i;

  int tid = threadIdx.x, lane = tid & 63, wv = tid >> 6;
  int srow = tid >> 2, scol = (tid & 3) * 8;
  const _Float16* gA = hbuf + (size_t)(row0 + srow) * F_ + scol;
  const _Float16* gB = w2h + (size_t)e * D_ * F_ + (size_t)(nb * BN + srow) * F_ + scol;
  const size_t FSTEP = (size_t)64 * F_;

  _Float16* dA0 = lA + (wv * 16) * BK;
  _Float16* dA1 = lA + (64 + wv * 16) * BK;
  _Float16* dB0 = lB + (wv * 16) * BK;
  _Float16* dB1 = lB + (64 + wv * 16) * BK;

  int wr = wv >> 1, wc = wv & 1;
  int fr = lane & 15, kq = (lane >> 4) * 8;
  const _Float16* pA = lA + (wr * 64 + fr) * BK + kq;
  const _Float16* pB = lB + (wc * 64 + fr) * BK + kq;

  f32x4 acc[4][4];
  f32x4 z = {0.f, 0.f, 0.f, 0.f};
#pragma unroll
  for (int m = 0; m < 4; ++m)
#pragma unroll
    for (int n = 0; n < 4; ++n) acc[m][n] = z;

  for (int ks = 0; ks < F_ / BK; ++ks) {
    int k0 = ks * BK;
    gload16(gA + k0, dA0);
    gload16(gA + FSTEP + k0, dA1);
    gload16(gB + k0, dB0);
    gload16(gB + FSTEP + k0, dB1);
    __syncthreads();
    half8 a[4], b[4];
#pragma unroll
    for (int m = 0; m < 4; ++m) a[m] = *(const half8*)(pA + m * 16 * BK);
#pragma unroll
    for (int n = 0; n < 4; ++n) b[n] = *(const half8*)(pB + n * 16 * BK);
#pragma unroll
    for (int m = 0; m < 4; ++m)
#pragma unroll
      for (int n = 0; n < 4; ++n)
        acc[m][n] = __builtin_amdgcn_mfma_f32_16x16x32_f16(a[m], b[n], acc[m][n], 0, 0, 0);
    __syncthreads();
  }

  int r0 = row0 + wr * 64 + (lane >> 4) * 4;
  int c0 = nb * BN + wc * 64 + (lane & 15);
#pragma unroll
  for (int m = 0; m < 4; ++m)
#pragma unroll
    for (int n = 0; n < 4; ++n)
#pragma unroll
      for (int i = 0; i < 4; ++i)
        ybuf[(size_t)(r0 + m * 16 + i) * D_ + (c0 + n * 16)] = acc[m][n][i];
}

// ---------------- combine: out[t] = g0*y[s0] + g1*y[s1] ----------------
__global__ __launch_bounds__(256) void combine_kernel(
    const float* __restrict__ ybuf, const int* __restrict__ slot_of,
    const float* __restrict__ tok_g, float* __restrict__ out) {
  int t = blockIdx.x, i = threadIdx.x;
  int s0 = slot_of[t * 2], s1 = slot_of[t * 2 + 1];
  float g0 = tok_g[t * 2], g1 = tok_g[t * 2 + 1];
  float4 a = ((const float4*)(ybuf + (size_t)s0 * D_))[i];
  float4 b = ((const float4*)(ybuf + (size_t)s1 * D_))[i];
  float4 r;
  r.x = g0 * a.x + g1 * b.x;
  r.y = g0 * a.y + g1 * b.y;
  r.z = g0 * a.z + g1 * b.z;
  r.w = g0 * a.w + g1 * b.w;
  ((float4*)(out + (size_t)t * D_))[i] = r;
}

extern "C" void kernel_launch(void* const* d_in, const int* in_sizes, int n_in,
                              void* d_out, int out_size, void* d_ws, size_t ws_size,
                              hipStream_t stream) {
  const float* x  = (const float*)d_in[0];
  const float* rw = (const float*)d_in[1];
  const float* rb = (const float*)d_in[2];
  const float* w1 = (const float*)d_in[3];
  const float* w2 = (const float*)d_in[4]; // note dict order: w2 before w3
  const float* w3 = (const float*)d_in[5];
  float* out = (float*)d_out;

  char* ws = (char*)d_ws;
  size_t off = 0;
  auto take = [&](size_t bytes) {
    char* p = ws + off;
    off = (off + bytes + 255) & ~(size_t)255;
    return p;
  };
  _Float16* x16 = (_Float16*)take((size_t)NTOK * D_ * 2);
  _Float16* w1h = (_Float16*)take((size_t)E_ * F_ * D_ * 2);
  _Float16* w3h = (_Float16*)take((size_t)E_ * F_ * D_ * 2);
  _Float16* w2h = (_Float16*)take((size_t)E_ * D_ * F_ * 2);
  _Float16* hbuf = (_Float16*)take((size_t)SLOT_CAP * F_ * 2);
  float* ybuf = (float*)take((size_t)SLOT_CAP * D_ * 4);
  int* slot_token = (int*)take((size_t)SLOT_CAP * 4);
  int* tok_e = (int*)take((size_t)NTOK * 2 * 4);
  float* tok_g = (float*)take((size_t)NTOK * 2 * 4);
  int* slot_of = (int*)take((size_t)NTOK * 2 * 4);
  int* counts = (int*)take(E_ * 4);
  int* cursor = (int*)take(E_ * 4);
  int* offs = (int*)take((E_ + 1) * 4);

  cvt_kernel<<<2048, 256, 0, stream>>>(x, x16, NTOK * D_ / 4);
  cvt_kernel<<<4096, 256, 0, stream>>>(w1, w1h, E_ * F_ * D_ / 4);
  cvt_kernel<<<4096, 256, 0, stream>>>(w3, w3h, E_ * F_ * D_ / 4);
  cvt_kernel<<<4096, 256, 0, stream>>>(w2, w2h, E_ * D_ * F_ / 4);
  init_kernel<<<(SLOT_CAP + 255) / 256, 256, 0, stream>>>(slot_token, counts, cursor);
  router_kernel<<<NTOK / 4, 256, 0, stream>>>(x, rw, rb, tok_e, tok_g, counts);
  scan_kernel<<<1, 64, 0, stream>>>(counts, offs);
  scatter_kernel<<<(NTOK * 2 + 255) / 256, 256, 0, stream>>>(tok_e, offs, cursor, slot_token, slot_of);
  gemm1_kernel<<<dim3(NRB, F_ / BN), 256, 0, stream>>>(x16, w1h, w3h, slot_token, offs, hbuf);
  gemm2_kernel<<<dim3(NRB, D_ / BN), 256, 0, stream>>>(hbuf, w2h, offs, ybuf);
  combine_kernel<<<NTOK, 256, 0, stream>>>(ybuf, slot_of, tok_g, out);
}

// Round 2
// 951.319 us; speedup vs baseline: 1.0824x; 1.0824x over previous
//
#include <hip/hip_runtime.h>
#include <hip/hip_fp16.h>

// MoE top-2 SwiGLU, MI355X. Sparse grouped-GEMM with 256-aligned expert segments.
// GEMMs: 8-wave 512-thread pipelined template (BK=32, 4 LDS buffers, distance-3
// prefetch via global_load_lds, counted vmcnt, XOR-swizzled LDS via pre-swizzled
// global source, setprio around MFMA clusters, XCD-chunked block swizzle).
// gemm1: virtual-N=8192 (w1/w3 interleaved at 16-col granularity) -> silu*mul -> h fp16.
// gemm2: h @ w2^T -> y fp32. fp16 MFMA 16x16x32, fp32 accum.

#define NTOK 8192
#define D_ 1024
#define F_ 4096
#define E_ 8
#define SLOT_CAP 18432  // 2*8192 + 8*256 (segments padded to 256)

using half8 = __attribute__((ext_vector_type(8))) _Float16;
using half4 = __attribute__((ext_vector_type(4))) _Float16;
using f32x4 = __attribute__((ext_vector_type(4))) float;

__device__ __forceinline__ void gload16(const void* g, void* l) {
  __builtin_amdgcn_global_load_lds((const __attribute__((address_space(1))) void*)g,
                                   (__attribute__((address_space(3))) void*)l, 16, 0, 0);
}

// ---------------- fp32 -> fp16 convert ----------------
__global__ __launch_bounds__(256) void cvt_kernel(const float* __restrict__ src,
                                                  _Float16* __restrict__ dst, int n4) {
  int i = blockIdx.x * 256 + threadIdx.x;
  int stride = gridDim.x * 256;
  for (; i < n4; i += stride) {
    float4 v = ((const float4*)src)[i];
    half4 h;
    h.x = (_Float16)v.x; h.y = (_Float16)v.y; h.z = (_Float16)v.z; h.w = (_Float16)v.w;
    ((half4*)dst)[i] = h;
  }
}

// w1,w3 -> interleaved virtual-row layout w13[e][8192][1024]:
// vrow = ((f>>4)<<5) | (sel<<4) | (f&15), sel 0=w1(gate), 1=w3(up).
__global__ __launch_bounds__(256) void cvt_w13_kernel(const float* __restrict__ w1,
                                                      const float* __restrict__ w3,
                                                      _Float16* __restrict__ w13, int n4) {
  int i = blockIdx.x * 256 + threadIdx.x;
  int stride = gridDim.x * 256;
  for (; i < n4; i += stride) {
    int d4 = i & 255;       // D/4 = 256
    int row = i >> 8;       // e*4096 + f
    int e = row >> 12, f = row & 4095;
    size_t vbase = ((size_t)e << 13) | ((size_t)(f >> 4) << 5) | (size_t)(f & 15);
    float4 v1 = ((const float4*)w1)[i];
    float4 v3 = ((const float4*)w3)[i];
    half4 h1, h3;
    h1.x = (_Float16)v1.x; h1.y = (_Float16)v1.y; h1.z = (_Float16)v1.z; h1.w = (_Float16)v1.w;
    h3.x = (_Float16)v3.x; h3.y = (_Float16)v3.y; h3.z = (_Float16)v3.z; h3.w = (_Float16)v3.w;
    ((half4*)w13)[vbase * 256 + d4] = h1;
    ((half4*)w13)[(vbase + 16) * 256 + d4] = h3;
  }
}

// ---------------- router ----------------
__global__ __launch_bounds__(256) void router_kernel(
    const float* __restrict__ x, const float* __restrict__ rw, const float* __restrict__ rbias,
    int* __restrict__ tok_e, float* __restrict__ tok_g, int* __restrict__ counts) {
  int wv = threadIdx.x >> 6, lane = threadIdx.x & 63;
  int t = blockIdx.x * 4 + wv;
  const float4* xr = (const float4*)(x + (size_t)t * D_);
  float acc[E_];
#pragma unroll
  for (int e = 0; e < E_; ++e) acc[e] = 0.f;
  for (int i = lane; i < D_ / 4; i += 64) {
    float4 xv = xr[i];
#pragma unroll
    for (int e = 0; e < E_; ++e) {
      float4 wv4 = ((const float4*)(rw + (size_t)e * D_))[i];
      acc[e] += xv.x * wv4.x + xv.y * wv4.y + xv.z * wv4.z + xv.w * wv4.w;
    }
  }
#pragma unroll
  for (int e = 0; e < E_; ++e) {
#pragma unroll
    for (int off = 32; off > 0; off >>= 1) acc[e] += __shfl_down(acc[e], off);
  }
  if (lane == 0) {
    float p[E_], mx = -1e30f;
#pragma unroll
    for (int e = 0; e < E_; ++e) { p[e] = acc[e] + rbias[e]; mx = fmaxf(mx, p[e]); }
#pragma unroll
    for (int e = 0; e < E_; ++e) p[e] = expf(p[e] - mx);
    int i0 = 0;
#pragma unroll
    for (int e = 1; e < E_; ++e) if (p[e] > p[i0]) i0 = e;
    int i1 = (i0 == 0) ? 1 : 0;
#pragma unroll
    for (int e = 0; e < E_; ++e) if (e != i0 && p[e] > p[i1]) i1 = e;
    float s = p[i0] + p[i1];
    tok_e[t * 2] = i0; tok_e[t * 2 + 1] = i1;
    tok_g[t * 2] = p[i0] / s; tok_g[t * 2 + 1] = p[i1] / s;
    atomicAdd(&counts[i0], 1); atomicAdd(&counts[i1], 1);
  }
}

__global__ void init_kernel(int* slot_token, int* counts, int* cursor) {
  int i = blockIdx.x * 256 + threadIdx.x;
  if (blockIdx.x == 0 && threadIdx.x < E_) { counts[threadIdx.x] = 0; cursor[threadIdx.x] = 0; }
  if (i < SLOT_CAP) slot_token[i] = 0;  // padding -> token 0 (finite garbage, never combined)
}

__global__ void scan_kernel(const int* __restrict__ counts, int* __restrict__ offs) {
  if (threadIdx.x == 0) {
    int o = 0;
    for (int e = 0; e < E_; ++e) { offs[e] = o; o += ((counts[e] + 255) / 256) * 256; }
    offs[E_] = o;
  }
}

__global__ void scatter_kernel(const int* __restrict__ tok_e, const int* __restrict__ offs,
                               int* __restrict__ cursor, int* __restrict__ slot_token,
                               int* __restrict__ slot_of) {
  int i = blockIdx.x * 256 + threadIdx.x;
  if (i >= NTOK * 2) return;
  int e = tok_e[i];
  int pos = offs[e] + atomicAdd(&cursor[e], 1);
  slot_token[pos] = i >> 1;
  slot_of[i] = pos;
}

// ---------------- pipelined grouped GEMM ----------------
// MFR: m-frags/wave (BM=32*MFR). MODE 0: gather-A + swiglu->h fp16. MODE 1: direct-A -> fp32.
// KD: K. NBN: N-block count. RPX: row-blocks per XCD. BEROWS: B rows per expert.
template <int MFR, int MODE, int KD, int NBN, int RPX, int BEROWS>
__global__ __launch_bounds__(512, 2) void moe_gemm_kernel(
    const _Float16* __restrict__ Amat, const _Float16* __restrict__ Bmat,
    const int* __restrict__ slot_token, const int* __restrict__ offs,
    void* __restrict__ outp) {
  constexpr int BM = MFR * 32;
  constexpr int BUFH = MFR * 1024 + 8192;  // halves per buffer: A (BM*32) + B (256*32)
  constexpr int NT = KD / 32;
  constexpr int AINS = MFR / 4;            // A stage instrs (512 thr * 16B = 128 rows each)
  __shared__ _Float16 lds[4 * BUFH];

  // bijective XCD-chunked swizzle; 8-row bands, rb-fastest within band for L2 reuse
  int id = blockIdx.x;
  int xcd = id & 7, idx = id >> 3;  // grid = 8 * RPX * NBN
  int band = idx / (8 * NBN);
  int i2 = idx - band * (8 * NBN);
  int rib = (RPX - band * 8) < 8 ? (RPX - band * 8) : 8;
  int nb = i2 / rib;
  int rloc = band * 8 + (i2 - nb * rib);
  int rb = xcd * RPX + rloc;
  int row0 = rb * BM;
  if (row0 >= offs[E_]) return;
  int e = 0;
#pragma unroll
  for (int i = 1; i < E_; ++i) if (row0 >= offs[i]) e = i;

  int t = threadIdx.x, l = t & 63, w = t >> 6;
  int wr = w >> 2, wc = w & 3;
  int srow = t >> 2;                              // 0..127 staging row
  int gsrc8 = ((l & 3) ^ ((l >> 3) & 3)) * 8;     // pre-swizzled source granule (T2, rule 21)

  const _Float16* aSrc[AINS];
  if constexpr (MODE == 0) {
    int tk0 = slot_token[row0 + srow];
    aSrc[0] = Amat + (size_t)tk0 * KD + gsrc8;
    if constexpr (AINS == 2) {
      int tk1 = slot_token[row0 + srow + 128];
      aSrc[1] = Amat + (size_t)tk1 * KD + gsrc8;
    }
  } else {
    aSrc[0] = Amat + (size_t)(row0 + srow) * KD + gsrc8;
    if constexpr (AINS == 2) aSrc[1] = Amat + (size_t)(row0 + srow + 128) * KD + gsrc8;
  }
  const _Float16* bSrc0 = Bmat + ((size_t)e * BEROWS + (size_t)nb * 256 + srow) * KD + gsrc8;
  const _Float16* bSrc1 = bSrc0 + (size_t)128 * KD;

  const int stA = w * 512;                 // wave staging dest (halves), +lane*8 by HW
  const int stB = MFR * 1024 + w * 512;

  auto stageA = [&](int bi, int tt) {
#pragma unroll
    for (int ins = 0; ins < AINS; ++ins)
      gload16(aSrc[ins] + tt * 32, &lds[bi * BUFH + stA + ins * 4096]);
  };
  auto stageB = [&](int bi, int tt) {
    gload16(bSrc0 + tt * 32, &lds[bi * BUFH + stB]);
    gload16(bSrc1 + tt * 32, &lds[bi * BUFH + stB + 4096]);
  };

  int fr = l & 15, kg = l >> 4;
  int swz8 = (kg ^ ((fr >> 1) & 3)) * 8;   // read-side swizzle matches source permutation
  const int rA = (wr * MFR * 16 + fr) * 32 + swz8;
  const int rB = MFR * 1024 + (wc * 64 + fr) * 32 + swz8;
  auto ldA = [&](int bi, int mi) { return *(const half8*)&lds[bi * BUFH + rA + mi * 512]; };
  auto ldB = [&](int bi, int ni) { return *(const half8*)&lds[bi * BUFH + rB + ni * 512]; };

  f32x4 acc[MFR][4];
#pragma unroll
  for (int m = 0; m < MFR; ++m)
#pragma unroll
    for (int n = 0; n < 4; ++n) acc[m][n] = (f32x4){0.f, 0.f, 0.f, 0.f};

  // prologue: stage tiles 0,1,2; wait tile 0 (keep 2 tiles in flight)
  stageA(0, 0); stageB(0, 0);
  stageA(1, 1); stageB(1, 1);
  stageA(2, 2); stageB(2, 2);
  if constexpr (AINS == 2) asm volatile("s_waitcnt vmcnt(8)" ::: "memory");
  else                     asm volatile("s_waitcnt vmcnt(6)" ::: "memory");
  __builtin_amdgcn_s_barrier();

  for (int j = 0; j < NT; ++j) {
    int bi = j & 3, bs = (j + 3) & 3;
    bool pre = (j + 3 < NT);
    int ahead = NT - 1 - j;
    half8 b[4];
    if constexpr (MFR == 8) {
      half8 a0[4];
#pragma unroll
      for (int mi = 0; mi < 4; ++mi) a0[mi] = ldA(bi, mi);
#pragma unroll
      for (int ni = 0; ni < 4; ++ni) b[ni] = ldB(bi, ni);
      if (pre) stageA(bs, j + 3);
      __builtin_amdgcn_s_barrier();
      asm volatile("s_waitcnt lgkmcnt(0)" ::: "memory");
      __builtin_amdgcn_s_setprio(1);
#pragma unroll
      for (int mi = 0; mi < 4; ++mi)
#pragma unroll
        for (int ni = 0; ni < 4; ++ni)
          acc[mi][ni] = __builtin_amdgcn_mfma_f32_16x16x32_f16(a0[mi], b[ni], acc[mi][ni], 0, 0, 0);
      __builtin_amdgcn_s_setprio(0);
      __builtin_amdgcn_s_barrier();
      half8 a1[4];
#pragma unroll
      for (int mi = 0; mi < 4; ++mi) a1[mi] = ldA(bi, mi + 4);
      if (pre) stageB(bs, j + 3);
      __builtin_amdgcn_s_barrier();
      asm volatile("s_waitcnt lgkmcnt(0)" ::: "memory");
      __builtin_amdgcn_s_setprio(1);
#pragma unroll
      for (int mi = 0; mi < 4; ++mi)
#pragma unroll
        for (int ni = 0; ni < 4; ++ni)
          acc[mi + 4][ni] =
              __builtin_amdgcn_mfma_f32_16x16x32_f16(a1[mi], b[ni], acc[mi + 4][ni], 0, 0, 0);
      __builtin_amdgcn_s_setprio(0);
    } else {
      half8 a0[4];
#pragma unroll
      for (int mi = 0; mi < 4; ++mi) a0[mi] = ldA(bi, mi);
#pragma unroll
      for (int ni = 0; ni < 4; ++ni) b[ni] = ldB(bi, ni);
      if (pre) { stageA(bs, j + 3); stageB(bs, j + 3); }
      __builtin_amdgcn_s_barrier();
      asm volatile("s_waitcnt lgkmcnt(0)" ::: "memory");
      __builtin_amdgcn_s_setprio(1);
#pragma unroll
      for (int mi = 0; mi < 4; ++mi)
#pragma unroll
        for (int ni = 0; ni < 4; ++ni)
          acc[mi][ni] = __builtin_amdgcn_mfma_f32_16x16x32_f16(a0[mi], b[ni], acc[mi][ni], 0, 0, 0);
      __builtin_amdgcn_s_setprio(0);
    }
    // tile boundary: ensure tile j+1 resident; keep later prefetches in flight
    if (ahead >= 3) {
      if constexpr (AINS == 2) asm volatile("s_waitcnt vmcnt(8)" ::: "memory");
      else                     asm volatile("s_waitcnt vmcnt(6)" ::: "memory");
      __builtin_amdgcn_s_barrier();
    } else if (ahead == 2) {
      if constexpr (AINS == 2) asm volatile("s_waitcnt vmcnt(4)" ::: "memory");
      else                     asm volatile("s_waitcnt vmcnt(3)" ::: "memory");
      __builtin_amdgcn_s_barrier();
    } else if (ahead == 1) {
      asm volatile("s_waitcnt vmcnt(0)" ::: "memory");
      __builtin_amdgcn_s_barrier();
    }
  }

  int q4 = (l >> 4) * 4;
  if constexpr (MODE == 0) {
    _Float16* hb = (_Float16*)outp;
#pragma unroll
    for (int mi = 0; mi < MFR; ++mi) {
      size_t rbase = (size_t)(row0 + wr * MFR * 16 + mi * 16 + q4);
#pragma unroll
      for (int p = 0; p < 2; ++p) {
        int fc = nb * 128 + (wc * 2 + p) * 16 + fr;
#pragma unroll
        for (int i = 0; i < 4; ++i) {
          float gv = acc[mi][2 * p][i];
          float hv = gv / (1.f + __expf(-gv)) * acc[mi][2 * p + 1][i];
          hb[(rbase + i) * (size_t)F_ + fc] = (_Float16)hv;
        }
      }
    }
  } else {
    float* yb = (float*)outp;
#pragma unroll
    for (int mi = 0; mi < MFR; ++mi) {
      size_t rbase = (size_t)(row0 + wr * MFR * 16 + mi * 16 + q4);
#pragma unroll
      for (int ni = 0; ni < 4; ++ni) {
        int col = nb * 256 + wc * 64 + ni * 16 + fr;
#pragma unroll
        for (int i = 0; i < 4; ++i)
          yb[(rbase + i) * (size_t)D_ + col] = acc[mi][ni][i];
      }
    }
  }
}

// ---------------- combine ----------------
__global__ __launch_bounds__(256) void combine_kernel(
    const float* __restrict__ ybuf, const int* __restrict__ slot_of,
    const float* __restrict__ tok_g, float* __restrict__ out) {
  int t = blockIdx.x, i = threadIdx.x;
  int s0 = slot_of[t * 2], s1 = slot_of[t * 2 + 1];
  float g0 = tok_g[t * 2], g1 = tok_g[t * 2 + 1];
  float4 a = ((const float4*)(ybuf + (size_t)s0 * D_))[i];
  float4 b = ((const float4*)(ybuf + (size_t)s1 * D_))[i];
  float4 r;
  r.x = g0 * a.x + g1 * b.x;
  r.y = g0 * a.y + g1 * b.y;
  r.z = g0 * a.z + g1 * b.z;
  r.w = g0 * a.w + g1 * b.w;
  ((float4*)(out + (size_t)t * D_))[i] = r;
}

extern "C" void kernel_launch(void* const* d_in, const int* in_sizes, int n_in,
                              void* d_out, int out_size, void* d_ws, size_t ws_size,
                              hipStream_t stream) {
  const float* x  = (const float*)d_in[0];
  const float* rw = (const float*)d_in[1];
  const float* rbc = (const float*)d_in[2];
  const float* w1 = (const float*)d_in[3];
  const float* w2 = (const float*)d_in[4];  // dict order: w2 before w3
  const float* w3 = (const float*)d_in[5];
  float* out = (float*)d_out;

  char* ws = (char*)d_ws;
  size_t off = 0;
  auto take = [&](size_t bytes) {
    char* p = ws + off;
    off = (off + bytes + 255) & ~(size_t)255;
    return p;
  };
  _Float16* x16 = (_Float16*)take((size_t)NTOK * D_ * 2);
  _Float16* w13 = (_Float16*)take((size_t)E_ * 2 * F_ * D_ * 2);   // 128 MB
  _Float16* w2h = (_Float16*)take((size_t)E_ * D_ * F_ * 2);       // 64 MB
  _Float16* hbuf = (_Float16*)take((size_t)SLOT_CAP * F_ * 2);     // 151 MB
  float* ybuf = (float*)take((size_t)SLOT_CAP * D_ * 4);           // 75.5 MB
  int* slot_token = (int*)take((size_t)SLOT_CAP * 4);
  int* tok_e = (int*)take((size_t)NTOK * 2 * 4);
  float* tok_g = (float*)take((size_t)NTOK * 2 * 4);
  int* slot_of = (int*)take((size_t)NTOK * 2 * 4);
  int* counts = (int*)take(E_ * 4);
  int* cursor = (int*)take(E_ * 4);
  int* offs = (int*)take((E_ + 1) * 4);

  cvt_kernel<<<2048, 256, 0, stream>>>(x, x16, NTOK * D_ / 4);
  cvt_w13_kernel<<<4096, 256, 0, stream>>>(w1, w3, w13, E_ * F_ * D_ / 4);
  cvt_kernel<<<4096, 256, 0, stream>>>(w2, w2h, E_ * D_ * F_ / 4);
  init_kernel<<<(SLOT_CAP + 255) / 256, 256, 0, stream>>>(slot_token, counts, cursor);
  router_kernel<<<NTOK / 4, 256, 0, stream>>>(x, rw, rbc, tok_e, tok_g, counts);
  scan_kernel<<<1, 64, 0, stream>>>(counts, offs);
  scatter_kernel<<<(NTOK * 2 + 255) / 256, 256, 0, stream>>>(tok_e, offs, cursor, slot_token, slot_of);
  // gemm1: M=18432cap x N_virt=8192 x K=1024, BM=256 -> grid 8*9*32
  moe_gemm_kernel<8, 0, 1024, 32, 9, 8192><<<2304, 512, 0, stream>>>(
      x16, w13, slot_token, offs, (void*)hbuf);
  // gemm2: M=18432cap x N=1024 x K=4096, BM=128 -> grid 8*18*4
  moe_gemm_kernel<4, 1, 4096, 4, 18, 1024><<<576, 512, 0, stream>>>(
      hbuf, w2h, slot_token, offs, (void*)ybuf);
  combine_kernel<<<NTOK, 256, 0, stream>>>(ybuf, slot_of, tok_g, out);
}